// Round 10
// baseline (189.382 us; speedup 1.0000x reference)
//
#include <hip/hip_runtime.h>

// ---------------------------------------------------------------------------
// MixedFeedForward: out = relu(x·(s⊙w0)^T + sb0⊙b0)·(s⊙w1)^T + sb1⊙b1
// r10: FINE phase interleave (faithful m201/8-phase port). r8's coarse
//      variant (1 barrier/ks-group, bulk reads then bulk MFMA) gave only
//      25% MfmaUtil — m196 measured coarse-split as -7..-27% vs fine.
//      Per K-tile: 4 phases x {ds_read(8|4 b128) -> 2 gload_lds ->
//      s_barrier -> setprio1 + 16 MFMA + setprio0 -> s_barrier};
//      vmcnt(4) only at ks-group boundaries (never 0 mid-loop).
//      Proven from r9: 2-way-free LDS swizzle (bank conflicts = 0).
// ---------------------------------------------------------------------------

typedef __attribute__((ext_vector_type(8))) short bf16x8;   // 8 bf16 = 4 VGPR
typedef __attribute__((ext_vector_type(4))) float f32x4;
typedef __attribute__((ext_vector_type(8))) unsigned short u16x8;

#define AS1 __attribute__((address_space(1)))
#define AS3 __attribute__((address_space(3)))

__device__ __forceinline__ unsigned short f2bf(float f) {
  unsigned int x = __float_as_uint(f);
  x += 0x7fffu + ((x >> 16) & 1u);        // round-to-nearest-even
  return (unsigned short)(x >> 16);
}

__device__ __forceinline__ void softmax3(const float* __restrict__ p, float* o) {
  float m = fmaxf(p[0], fmaxf(p[1], p[2]));
  float e0 = expf(p[0] - m), e1 = expf(p[1] - m), e2 = expf(p[2] - m);
  float inv = 1.0f / (e0 + e1 + e2);
  o[0] = e0 * inv; o[1] = e1 * inv; o[2] = e2 * inv;
}

// s(h,d); sval(h,0) = bm0[h] row-bias scale; sval(0,d) = bm1[d] col-bias scale
__device__ __forceinline__ float sval(int h, int d, const float a[3], const float b[3]) {
  constexpr int E[3] = {512, 768, 1024};
  constexpr int R[3] = {2, 3, 4};
  float s = 0.f;
#pragma unroll
  for (int ie = 0; ie < 3; ++ie) {
    if (d < E[ie]) {
      float t = 0.f;
#pragma unroll
      for (int ir = 0; ir < 3; ++ir)
        if (h < E[ie] * R[ir]) t += b[ir];
      s += a[ie] * t;
    }
  }
  return s;
}

// ---------------- fused prep kernel --------------------------------------

__device__ __forceinline__ void cvt8(const float* __restrict__ src,
                                     unsigned short* __restrict__ dst,
                                     size_t base, float s) {
  const f32x4* p = (const f32x4*)(src + base);
  f32x4 v0 = p[0], v1 = p[1];
  u16x8 r;
#pragma unroll
  for (int j = 0; j < 4; ++j) { r[j] = f2bf(v0[j] * s); r[4 + j] = f2bf(v1[j] * s); }
  *(u16x8*)(dst + base) = r;
}

__global__ __launch_bounds__(256) void conv_all(const float* __restrict__ x,
                                                const float* __restrict__ w0,
                                                const float* __restrict__ b0,
                                                const float* __restrict__ w1,
                                                const float* __restrict__ b1,
                                                const float* __restrict__ ae,
                                                const float* __restrict__ am,
                                                unsigned short* __restrict__ xb,
                                                unsigned short* __restrict__ w0e,
                                                unsigned short* __restrict__ w1e,
                                                float* __restrict__ bb0,
                                                float* __restrict__ bb1) {
  int t = blockIdx.x * 256 + threadIdx.x;
  float a[3], b[3];
  softmax3(ae, a); softmax3(am, b);
  if (t < 524288) {
    cvt8(x, xb, (size_t)t * 8, 1.0f);
  } else if (t < 1048576) {
    int base = (t - 524288) * 8;
    cvt8(w0, w0e, base, sval(base >> 10, base & 1023, a, b));   // (h,d)
  } else if (t < 1572864) {
    int base = (t - 1048576) * 8;
    cvt8(w1, w1e, base, sval(base & 4095, base >> 12, a, b));   // (d,h): s(h,d)
  } else if (t < 1573504) {
    int base = (t - 1572864) * 8;
#pragma unroll
    for (int j = 0; j < 8; ++j) {
      int i = base + j;
      if (i < 4096) bb0[i] = sval(i, 0, a, b) * b0[i];
      else          bb1[i - 4096] = sval(0, i - 4096, a, b) * b1[i - 4096];
    }
  }
}

// ---------------- 256x256 fine-phase bf16 MFMA GEMM, B^T layout -------------
// 8 waves: wm=(wid>>2)*128, wn=(wid&3)*64. LDS 128KiB dynamic:
// As[2 buf][2 ks][256 rows][32 elems] then Bs same.
// Swizzle: storage 16B-chunk cs = cl ^ ((row>>1)&3) (involution, r9: 0 conflicts).
// MODE 0: +bias, relu, bf16. MODE 1: +bias, f32. MODE 2: f32 partial at
// Cout + blockIdx.z*M*N, kbeg = blockIdx.z*Ksub.

template <int MODE>
__global__ __launch_bounds__(512, 2) void gemm256(const unsigned short* __restrict__ A,
                                                  const unsigned short* __restrict__ B,
                                                  const float* __restrict__ bias,
                                                  void* __restrict__ Cout,
                                                  int M, int N, int K, int Ksub) {
  extern __shared__ unsigned short lds[];   // 65536 ushorts = 128 KiB

  const int tid  = threadIdx.x;
  const int lane = tid & 63;
  const int wid  = tid >> 6;
  const int m0   = blockIdx.x * 256;
  const int n0   = blockIdx.y * 256;
  const int wm   = (wid >> 2) * 128;
  const int wn   = (wid & 3) * 64;
  const int kbeg = (MODE == 2) ? blockIdx.z * Ksub : 0;
  const int nt   = Ksub >> 6;

  f32x4 acc[8][4] = {};

  // staging: thread t -> row t>>2, storage chunk t&3; global source chunk
  // inverse-swizzled: (t&3) ^ ((t>>3)&3)   [(row>>1)&3]
  const int srow   = tid >> 2;                       // 0..127
  const int schunk = (tid & 3) ^ ((tid >> 3) & 3);
  const unsigned short* Ag = A + (size_t)(m0 + srow) * K + schunk * 8;
  const unsigned short* Bg = B + (size_t)(n0 + srow) * K + schunk * 8;
  const size_t rstep = (size_t)128 * K;

  // one half-tile (A or B, one ks) = 2 gload_lds (256 rows x 32 elems)
  auto stage2 = [&](int ldsbase, const unsigned short* g, int k) {
    unsigned short* d = lds + ldsbase + tid * 8;     // linear dest
    __builtin_amdgcn_global_load_lds((const AS1 void*)(g + k),
                                     (AS3 void*)d, 16, 0, 0);
    __builtin_amdgcn_global_load_lds((const AS1 void*)(g + rstep + k),
                                     (AS3 void*)(d + 4096), 16, 0, 0);
  };

  // read swizzle: col-chunk XOR (lane>>1)&3  [= (row>>1)&3, rows 16-aligned]
  const int rc = ((lane >> 4) * 8) ^ (((lane >> 1) & 3) << 3);
  const int ra = (lane & 15) * 32 + rc;

  // prologue: tile 0 halves in ledger order [A-K0, B-K0, A-K1, B-K1]
  stage2(0, Ag, kbeg);
  stage2(32768, Bg, kbeg);
  stage2(8192, Ag, kbeg + 32);
  stage2(32768 + 8192, Bg, kbeg + 32);

  int buf = 0;
  for (int T = 0; T < nt; ++T) {
    const int kn = kbeg + T * 64 + 64;
    const bool pf = (T + 1 < nt);
    bf16x8 af[4], bfr[4];
    const int ab  = buf * 2 * 8192;            // As ks=0 base (elems)
    const int bbq = 32768 + buf * 2 * 8192;    // Bs ks=0 base
    const int nb  = (buf ^ 1) * 2 * 8192;      // next-buf As base

    // ============ phase 0 (ks=0, m-tiles 0..3) ============
    asm volatile("s_waitcnt vmcnt(4)" ::: "memory");   // A0,B0 of T landed
    __builtin_amdgcn_s_barrier();
    asm volatile("" ::: "memory");
#pragma unroll
    for (int n = 0; n < 4; ++n) bfr[n] = *(const bf16x8*)&lds[bbq + (wn + n * 16) * 32 + ra];
#pragma unroll
    for (int m = 0; m < 4; ++m) af[m] = *(const bf16x8*)&lds[ab + (wm + m * 16) * 32 + ra];
    if (pf) stage2(nb, Ag, kn);                        // A-half0 of T+1
    __builtin_amdgcn_s_barrier();
    asm volatile("" ::: "memory");
    __builtin_amdgcn_s_setprio(1);
#pragma unroll
    for (int m = 0; m < 4; ++m)
#pragma unroll
      for (int n = 0; n < 4; ++n)
        acc[m][n] = __builtin_amdgcn_mfma_f32_16x16x32_bf16(af[m], bfr[n], acc[m][n], 0, 0, 0);
    __builtin_amdgcn_s_setprio(0);

    // ============ phase 1 (ks=0, m-tiles 4..7) ============
    __builtin_amdgcn_s_barrier();
    asm volatile("" ::: "memory");
#pragma unroll
    for (int m = 0; m < 4; ++m) af[m] = *(const bf16x8*)&lds[ab + (wm + 64 + m * 16) * 32 + ra];
    if (pf) stage2(32768 + nb, Bg, kn);                // B-half0 of T+1
    __builtin_amdgcn_s_barrier();
    asm volatile("" ::: "memory");
    __builtin_amdgcn_s_setprio(1);
#pragma unroll
    for (int m = 0; m < 4; ++m)
#pragma unroll
      for (int n = 0; n < 4; ++n)
        acc[4 + m][n] = __builtin_amdgcn_mfma_f32_16x16x32_bf16(af[m], bfr[n], acc[4 + m][n], 0, 0, 0);
    __builtin_amdgcn_s_setprio(0);

    // ============ phase 2 (ks=1, m-tiles 0..3) ============
    if (pf) { asm volatile("s_waitcnt vmcnt(4)" ::: "memory"); }  // A1,B1 of T
    else    { asm volatile("s_waitcnt vmcnt(0)" ::: "memory"); }
    __builtin_amdgcn_s_barrier();
    asm volatile("" ::: "memory");
#pragma unroll
    for (int n = 0; n < 4; ++n) bfr[n] = *(const bf16x8*)&lds[bbq + 8192 + (wn + n * 16) * 32 + ra];
#pragma unroll
    for (int m = 0; m < 4; ++m) af[m] = *(const bf16x8*)&lds[ab + 8192 + (wm + m * 16) * 32 + ra];
    if (pf) stage2(nb + 8192, Ag, kn + 32);            // A-half1 of T+1
    __builtin_amdgcn_s_barrier();
    asm volatile("" ::: "memory");
    __builtin_amdgcn_s_setprio(1);
#pragma unroll
    for (int m = 0; m < 4; ++m)
#pragma unroll
      for (int n = 0; n < 4; ++n)
        acc[m][n] = __builtin_amdgcn_mfma_f32_16x16x32_bf16(af[m], bfr[n], acc[m][n], 0, 0, 0);
    __builtin_amdgcn_s_setprio(0);

    // ============ phase 3 (ks=1, m-tiles 4..7) ============
    __builtin_amdgcn_s_barrier();
    asm volatile("" ::: "memory");
#pragma unroll
    for (int m = 0; m < 4; ++m) af[m] = *(const bf16x8*)&lds[ab + 8192 + (wm + 64 + m * 16) * 32 + ra];
    if (pf) stage2(32768 + nb + 8192, Bg, kn + 32);    // B-half1 of T+1
    __builtin_amdgcn_s_barrier();
    asm volatile("" ::: "memory");
    __builtin_amdgcn_s_setprio(1);
#pragma unroll
    for (int m = 0; m < 4; ++m)
#pragma unroll
      for (int n = 0; n < 4; ++n)
        acc[4 + m][n] = __builtin_amdgcn_mfma_f32_16x16x32_bf16(af[m], bfr[n], acc[4 + m][n], 0, 0, 0);
    __builtin_amdgcn_s_setprio(0);

    buf ^= 1;
  }

  // epilogue: C/D layout col=lane&15, row=(lane>>4)*4+reg  [m89-verified]
  const int crow = (lane >> 4) * 4;
  const int ccol = lane & 15;
#pragma unroll
  for (int mi = 0; mi < 8; ++mi) {
#pragma unroll
    for (int n = 0; n < 4; ++n) {
      const int gr = m0 + wm + mi * 16 + crow;
      const int gc = n0 + wn + n * 16 + ccol;
      if (MODE == 0) {
        const float bv = bias[gc];
        unsigned short* H = (unsigned short*)Cout;
#pragma unroll
        for (int r = 0; r < 4; ++r) {
          float v = fmaxf(acc[mi][n][r] + bv, 0.f);
          H[(size_t)(gr + r) * N + gc] = f2bf(v);
        }
      } else if (MODE == 1) {
        const float bv = bias[gc];
        float* C = (float*)Cout;
#pragma unroll
        for (int r = 0; r < 4; ++r)
          C[(size_t)(gr + r) * N + gc] = acc[mi][n][r] + bv;
      } else {
        float* P = (float*)Cout + (size_t)blockIdx.z * M * N;
#pragma unroll
        for (int r = 0; r < 4; ++r)
          P[(size_t)(gr + r) * N + gc] = acc[mi][n][r];
      }
    }
  }
}

// reduce 4 f32 partials + bias -> out.  n4 = MN/4 in f32x4 units.
__global__ __launch_bounds__(256) void reduce_k(const float* __restrict__ P,
                                                const float* __restrict__ bb1,
                                                float* __restrict__ out,
                                                int n4) {
  const f32x4* p = (const f32x4*)P;
  const f32x4* bv = (const f32x4*)bb1;
  f32x4* o = (f32x4*)out;
  for (int i = blockIdx.x * 256 + threadIdx.x; i < n4; i += gridDim.x * 256) {
    f32x4 v = p[i];
    v += p[i + n4];
    v += p[i + 2 * n4];
    v += p[i + 3 * n4];
    v += bv[i & 255];                  // col = (i*4) % 1024
    o[i] = v;
  }
}

// ---------------------------------------------------------------------------

extern "C" void kernel_launch(void* const* d_in, const int* in_sizes, int n_in,
                              void* d_out, int out_size, void* d_ws, size_t ws_size,
                              hipStream_t stream) {
  const float* x  = (const float*)d_in[0];   // [8,512,1024]
  const float* w0 = (const float*)d_in[1];   // [4096,1024]
  const float* b0 = (const float*)d_in[2];   // [4096]
  const float* w1 = (const float*)d_in[3];   // [1024,4096]
  const float* b1 = (const float*)d_in[4];   // [1024]
  const float* ae = (const float*)d_in[5];   // [3]
  const float* am = (const float*)d_in[6];   // [3]

  char* ws = (char*)d_ws;
  unsigned short* xb   = (unsigned short*)(ws);                    //  8 MiB
  unsigned short* w0e  = (unsigned short*)(ws + (8u  << 20));      //  8 MiB
  unsigned short* w1e  = (unsigned short*)(ws + (16u << 20));      //  8 MiB
  unsigned short* Hbuf = (unsigned short*)(ws + (24u << 20));      // 32 MiB
  float* bb0 = (float*)(ws + (56u << 20));                         // 16 KiB
  float* bb1 = (float*)(ws + (56u << 20) + 16384);                 //  4 KiB
  float* part = (float*)(ws + (57u << 20));                        // 64 MiB (split-K)
  const size_t WS_NEEDED = (57u << 20) + (64u << 20);              // 121 MiB

  conv_all<<<6147, 256, 0, stream>>>(x, w0, b0, w1, b1, ae, am,
                                     xb, w0e, w1e, bb0, bb1);

  dim3 g1(16, 16);  // M/256 x N/256
  gemm256<0><<<g1, 512, 131072, stream>>>(xb, w0e, bb0, Hbuf, 4096, 4096, 1024, 1024);

  if (ws_size >= WS_NEEDED) {
    // split-K x4: 16x4x4 = 256 blocks (1/CU, 8 waves each)
    dim3 g2(16, 4, 4);
    gemm256<2><<<g2, 512, 131072, stream>>>(Hbuf, w1e, nullptr, part, 4096, 1024, 4096, 1024);
    reduce_k<<<2048, 256, 0, stream>>>(part, bb1, (float*)d_out, 1024 * 1024);
  } else {
    dim3 g2(16, 4);
    gemm256<1><<<g2, 512, 131072, stream>>>(Hbuf, w1e, bb1, d_out, 4096, 1024, 4096, 4096);
  }
}

// Round 12
// 188.635 us; speedup vs baseline: 1.0040x; 1.0040x over previous
//
#include <hip/hip_runtime.h>

// ---------------------------------------------------------------------------
// MixedFeedForward: out = relu(x·(s⊙w0)^T + sb0⊙b0)·(s⊙w1)^T + sb1⊙b1
// r11: GEMM1 keeps r10's 256² fine-phase (proven 43.8µs) + XCD rect-swizzle.
//      GEMM2 -> 128² fine-phase SK2 (512 blocks, 2 blocks/CU via 64KB LDS):
//      nt=32 amortizes prologue; inter-block overlap fills barrier stalls
//      (m114); partial traffic halved (reduce 80->48MB). XCD rect-swizzle on
//      both. r10 evidence: fine-phase -17%, conflicts 0, MfmaUtil 28%.
// ---------------------------------------------------------------------------

typedef __attribute__((ext_vector_type(8))) short bf16x8;   // 8 bf16 = 4 VGPR
typedef __attribute__((ext_vector_type(4))) float f32x4;
typedef __attribute__((ext_vector_type(8))) unsigned short u16x8;

#define AS1 __attribute__((address_space(1)))
#define AS3 __attribute__((address_space(3)))

__device__ __forceinline__ unsigned short f2bf(float f) {
  unsigned int x = __float_as_uint(f);
  x += 0x7fffu + ((x >> 16) & 1u);        // round-to-nearest-even
  return (unsigned short)(x >> 16);
}

__device__ __forceinline__ void softmax3(const float* __restrict__ p, float* o) {
  float m = fmaxf(p[0], fmaxf(p[1], p[2]));
  float e0 = expf(p[0] - m), e1 = expf(p[1] - m), e2 = expf(p[2] - m);
  float inv = 1.0f / (e0 + e1 + e2);
  o[0] = e0 * inv; o[1] = e1 * inv; o[2] = e2 * inv;
}

// s(h,d); sval(h,0) = bm0[h] row-bias scale; sval(0,d) = bm1[d] col-bias scale
__device__ __forceinline__ float sval(int h, int d, const float a[3], const float b[3]) {
  constexpr int E[3] = {512, 768, 1024};
  constexpr int R[3] = {2, 3, 4};
  float s = 0.f;
#pragma unroll
  for (int ie = 0; ie < 3; ++ie) {
    if (d < E[ie]) {
      float t = 0.f;
#pragma unroll
      for (int ir = 0; ir < 3; ++ir)
        if (h < E[ie] * R[ir]) t += b[ir];
      s += a[ie] * t;
    }
  }
  return s;
}

// ---------------- fused prep kernel --------------------------------------

__device__ __forceinline__ void cvt8(const float* __restrict__ src,
                                     unsigned short* __restrict__ dst,
                                     size_t base, float s) {
  const f32x4* p = (const f32x4*)(src + base);
  f32x4 v0 = p[0], v1 = p[1];
  u16x8 r;
#pragma unroll
  for (int j = 0; j < 4; ++j) { r[j] = f2bf(v0[j] * s); r[4 + j] = f2bf(v1[j] * s); }
  *(u16x8*)(dst + base) = r;
}

__global__ __launch_bounds__(256) void conv_all(const float* __restrict__ x,
                                                const float* __restrict__ w0,
                                                const float* __restrict__ b0,
                                                const float* __restrict__ w1,
                                                const float* __restrict__ b1,
                                                const float* __restrict__ ae,
                                                const float* __restrict__ am,
                                                unsigned short* __restrict__ xb,
                                                unsigned short* __restrict__ w0e,
                                                unsigned short* __restrict__ w1e,
                                                float* __restrict__ bb0,
                                                float* __restrict__ bb1) {
  int t = blockIdx.x * 256 + threadIdx.x;
  float a[3], b[3];
  softmax3(ae, a); softmax3(am, b);
  if (t < 524288) {
    cvt8(x, xb, (size_t)t * 8, 1.0f);
  } else if (t < 1048576) {
    int base = (t - 524288) * 8;
    cvt8(w0, w0e, base, sval(base >> 10, base & 1023, a, b));   // (h,d)
  } else if (t < 1572864) {
    int base = (t - 1048576) * 8;
    cvt8(w1, w1e, base, sval(base & 4095, base >> 12, a, b));   // (d,h): s(h,d)
  } else if (t < 1573504) {
    int base = (t - 1572864) * 8;
#pragma unroll
    for (int j = 0; j < 8; ++j) {
      int i = base + j;
      if (i < 4096) bb0[i] = sval(i, 0, a, b) * b0[i];
      else          bb1[i - 4096] = sval(0, i - 4096, a, b) * b1[i - 4096];
    }
  }
}

// ---------------- 256x256 fine-phase bf16 MFMA GEMM (GEMM1 / fallback) ------
// Structure identical to r10 (43.8µs proven) + XCD 8x4-rect swizzle (MODE0).

template <int MODE>
__global__ __launch_bounds__(512, 2) void gemm256(const unsigned short* __restrict__ A,
                                                  const unsigned short* __restrict__ B,
                                                  const float* __restrict__ bias,
                                                  void* __restrict__ Cout,
                                                  int M, int N, int K, int Ksub) {
  extern __shared__ unsigned short lds[];   // 65536 ushorts = 128 KiB

  const int tid  = threadIdx.x;
  const int lane = tid & 63;
  const int wid  = tid >> 6;
  int bx = blockIdx.x, by = blockIdx.y;
  if (MODE == 0) {                 // grid 16x16: 8x4 rect per XCD (bijective)
    int lb = by * 16 + bx, xcd = lb & 7, p = lb >> 3;
    bx = (xcd & 1) * 8 + (p & 7);
    by = (xcd >> 1) * 4 + (p >> 3);
  }
  const int m0   = bx * 256;
  const int n0   = by * 256;
  const int wm   = (wid >> 2) * 128;
  const int wn   = (wid & 3) * 64;
  const int kbeg = (MODE == 2) ? blockIdx.z * Ksub : 0;
  const int nt   = Ksub >> 6;

  f32x4 acc[8][4] = {};

  const int srow   = tid >> 2;                       // 0..127
  const int schunk = (tid & 3) ^ ((tid >> 3) & 3);   // inverse swizzle
  const unsigned short* Ag = A + (size_t)(m0 + srow) * K + schunk * 8;
  const unsigned short* Bg = B + (size_t)(n0 + srow) * K + schunk * 8;
  const size_t rstep = (size_t)128 * K;

  auto stage2 = [&](int ldsbase, const unsigned short* g, int k) {
    unsigned short* d = lds + ldsbase + tid * 8;     // linear dest
    __builtin_amdgcn_global_load_lds((const AS1 void*)(g + k),
                                     (AS3 void*)d, 16, 0, 0);
    __builtin_amdgcn_global_load_lds((const AS1 void*)(g + rstep + k),
                                     (AS3 void*)(d + 4096), 16, 0, 0);
  };

  const int rc = ((lane >> 4) * 8) ^ (((lane >> 1) & 3) << 3);
  const int ra = (lane & 15) * 32 + rc;

  stage2(0, Ag, kbeg);
  stage2(32768, Bg, kbeg);
  stage2(8192, Ag, kbeg + 32);
  stage2(32768 + 8192, Bg, kbeg + 32);

  int buf = 0;
  for (int T = 0; T < nt; ++T) {
    const int kn = kbeg + T * 64 + 64;
    const bool pf = (T + 1 < nt);
    bf16x8 af[4], bfr[4];
    const int ab  = buf * 2 * 8192;
    const int bbq = 32768 + buf * 2 * 8192;
    const int nb  = (buf ^ 1) * 2 * 8192;

    // phase 0 (ks=0, m 0..3)
    asm volatile("s_waitcnt vmcnt(4)" ::: "memory");
    __builtin_amdgcn_s_barrier();
    asm volatile("" ::: "memory");
#pragma unroll
    for (int n = 0; n < 4; ++n) bfr[n] = *(const bf16x8*)&lds[bbq + (wn + n * 16) * 32 + ra];
#pragma unroll
    for (int m = 0; m < 4; ++m) af[m] = *(const bf16x8*)&lds[ab + (wm + m * 16) * 32 + ra];
    if (pf) stage2(nb, Ag, kn);
    __builtin_amdgcn_s_barrier();
    asm volatile("" ::: "memory");
    __builtin_amdgcn_s_setprio(1);
#pragma unroll
    for (int m = 0; m < 4; ++m)
#pragma unroll
      for (int n = 0; n < 4; ++n)
        acc[m][n] = __builtin_amdgcn_mfma_f32_16x16x32_bf16(af[m], bfr[n], acc[m][n], 0, 0, 0);
    __builtin_amdgcn_s_setprio(0);

    // phase 1 (ks=0, m 4..7)
    __builtin_amdgcn_s_barrier();
    asm volatile("" ::: "memory");
#pragma unroll
    for (int m = 0; m < 4; ++m) af[m] = *(const bf16x8*)&lds[ab + (wm + 64 + m * 16) * 32 + ra];
    if (pf) stage2(32768 + nb, Bg, kn);
    __builtin_amdgcn_s_barrier();
    asm volatile("" ::: "memory");
    __builtin_amdgcn_s_setprio(1);
#pragma unroll
    for (int m = 0; m < 4; ++m)
#pragma unroll
      for (int n = 0; n < 4; ++n)
        acc[4 + m][n] = __builtin_amdgcn_mfma_f32_16x16x32_bf16(af[m], bfr[n], acc[4 + m][n], 0, 0, 0);
    __builtin_amdgcn_s_setprio(0);

    // phase 2 (ks=1, m 0..3)
    if (pf) { asm volatile("s_waitcnt vmcnt(4)" ::: "memory"); }
    else    { asm volatile("s_waitcnt vmcnt(0)" ::: "memory"); }
    __builtin_amdgcn_s_barrier();
    asm volatile("" ::: "memory");
#pragma unroll
    for (int n = 0; n < 4; ++n) bfr[n] = *(const bf16x8*)&lds[bbq + 8192 + (wn + n * 16) * 32 + ra];
#pragma unroll
    for (int m = 0; m < 4; ++m) af[m] = *(const bf16x8*)&lds[ab + 8192 + (wm + m * 16) * 32 + ra];
    if (pf) stage2(nb + 8192, Ag, kn + 32);
    __builtin_amdgcn_s_barrier();
    asm volatile("" ::: "memory");
    __builtin_amdgcn_s_setprio(1);
#pragma unroll
    for (int m = 0; m < 4; ++m)
#pragma unroll
      for (int n = 0; n < 4; ++n)
        acc[m][n] = __builtin_amdgcn_mfma_f32_16x16x32_bf16(af[m], bfr[n], acc[m][n], 0, 0, 0);
    __builtin_amdgcn_s_setprio(0);

    // phase 3 (ks=1, m 4..7)
    __builtin_amdgcn_s_barrier();
    asm volatile("" ::: "memory");
#pragma unroll
    for (int m = 0; m < 4; ++m) af[m] = *(const bf16x8*)&lds[ab + 8192 + (wm + 64 + m * 16) * 32 + ra];
    if (pf) stage2(32768 + nb + 8192, Bg, kn + 32);
    __builtin_amdgcn_s_barrier();
    asm volatile("" ::: "memory");
    __builtin_amdgcn_s_setprio(1);
#pragma unroll
    for (int m = 0; m < 4; ++m)
#pragma unroll
      for (int n = 0; n < 4; ++n)
        acc[4 + m][n] = __builtin_amdgcn_mfma_f32_16x16x32_bf16(af[m], bfr[n], acc[4 + m][n], 0, 0, 0);
    __builtin_amdgcn_s_setprio(0);

    buf ^= 1;
  }

  const int crow = (lane >> 4) * 4;
  const int ccol = lane & 15;
#pragma unroll
  for (int mi = 0; mi < 8; ++mi) {
#pragma unroll
    for (int n = 0; n < 4; ++n) {
      const int gr = m0 + wm + mi * 16 + crow;
      const int gc = n0 + wn + n * 16 + ccol;
      if (MODE == 0) {
        const float bv = bias[gc];
        unsigned short* H = (unsigned short*)Cout;
#pragma unroll
        for (int r = 0; r < 4; ++r) {
          float v = fmaxf(acc[mi][n][r] + bv, 0.f);
          H[(size_t)(gr + r) * N + gc] = f2bf(v);
        }
      } else if (MODE == 1) {
        const float bv = bias[gc];
        float* C = (float*)Cout;
#pragma unroll
        for (int r = 0; r < 4; ++r)
          C[(size_t)(gr + r) * N + gc] = acc[mi][n][r] + bv;
      } else {
        float* P = (float*)Cout + (size_t)blockIdx.z * M * N;
#pragma unroll
        for (int r = 0; r < 4; ++r)
          P[(size_t)(gr + r) * N + gc] = acc[mi][n][r];
      }
    }
  }
}

// ---------------- 128x128 fine-phase GEMM2 partial kernel (SK2) -------------
// 4 waves (2Mx2N, 64x64 each), 64KB static LDS -> 2 blocks/CU. 2 phases/K-tile
// x {vmcnt(4); BAR; 8 ds_read; 2x stage2; BAR; setprio+16 MFMA}. nt=32.
// Writes f32 partial at P + z*M*N.

__global__ __launch_bounds__(256, 2) void gemm128p(const unsigned short* __restrict__ A,
                                                   const unsigned short* __restrict__ B,
                                                   float* __restrict__ P,
                                                   int M, int N, int K, int Ksub) {
  __shared__ unsigned short lds[32768];   // As 16384 | Bs 16384 (64 KiB)

  const int tid  = threadIdx.x;
  const int lane = tid & 63;
  const int wid  = tid >> 6;
  // grid (32,8,z): 8x4 rect per XCD within each z-slice (bijective, 256%8==0)
  int lb = blockIdx.y * 32 + blockIdx.x, xcd = lb & 7, p = lb >> 3;
  const int bx = (xcd & 3) * 8 + (p & 7);
  const int by = (xcd >> 2) * 4 + (p >> 3);
  const int m0   = bx * 128;
  const int n0   = by * 128;
  const int wm   = (wid >> 1) * 64;
  const int wn   = (wid & 1) * 64;
  const int kbeg = blockIdx.z * Ksub;
  const int nt   = Ksub >> 6;

  f32x4 acc[4][4] = {};

  const int srow   = tid >> 2;                       // 0..63
  const int schunk = (tid & 3) ^ ((tid >> 3) & 3);
  const unsigned short* Ag = A + (size_t)(m0 + srow) * K + schunk * 8;
  const unsigned short* Bg = B + (size_t)(n0 + srow) * K + schunk * 8;
  const size_t rstep = (size_t)64 * K;

  auto stage2 = [&](int ldsbase, const unsigned short* g, int k) {
    unsigned short* d = lds + ldsbase + tid * 8;     // linear dest
    __builtin_amdgcn_global_load_lds((const AS1 void*)(g + k),
                                     (AS3 void*)d, 16, 0, 0);
    __builtin_amdgcn_global_load_lds((const AS1 void*)(g + rstep + k),
                                     (AS3 void*)(d + 2048), 16, 0, 0);
  };

  const int rc = ((lane >> 4) * 8) ^ (((lane >> 1) & 3) << 3);
  const int ra = (lane & 15) * 32 + rc;

  // prologue: [A0,B0,A1,B1] of tile 0 (8 loads)
  stage2(0, Ag, kbeg);
  stage2(16384, Bg, kbeg);
  stage2(4096, Ag, kbeg + 32);
  stage2(16384 + 4096, Bg, kbeg + 32);

  int buf = 0;
  for (int T = 0; T < nt; ++T) {
    const int kn = kbeg + T * 64 + 64;
    const bool pf = (T + 1 < nt);
    bf16x8 af[4], bfr[4];
    const int ab  = buf * 2 * 4096;
    const int bbq = 16384 + buf * 2 * 4096;
    const int nb  = (buf ^ 1) * 2 * 4096;

    // phase 0 (ks=0)
    asm volatile("s_waitcnt vmcnt(4)" ::: "memory");   // A0,B0 of T landed
    __builtin_amdgcn_s_barrier();
    asm volatile("" ::: "memory");
#pragma unroll
    for (int n = 0; n < 4; ++n) bfr[n] = *(const bf16x8*)&lds[bbq + (wn + n * 16) * 32 + ra];
#pragma unroll
    for (int m = 0; m < 4; ++m) af[m] = *(const bf16x8*)&lds[ab + (wm + m * 16) * 32 + ra];
    if (pf) { stage2(nb, Ag, kn); stage2(16384 + nb, Bg, kn); }
    __builtin_amdgcn_s_barrier();
    asm volatile("" ::: "memory");
    __builtin_amdgcn_s_setprio(1);
#pragma unroll
    for (int m = 0; m < 4; ++m)
#pragma unroll
      for (int n = 0; n < 4; ++n)
        acc[m][n] = __builtin_amdgcn_mfma_f32_16x16x32_bf16(af[m], bfr[n], acc[m][n], 0, 0, 0);
    __builtin_amdgcn_s_setprio(0);

    // phase 1 (ks=1)
    if (pf) { asm volatile("s_waitcnt vmcnt(4)" ::: "memory"); }  // A1,B1 of T
    else    { asm volatile("s_waitcnt vmcnt(0)" ::: "memory"); }
    __builtin_amdgcn_s_barrier();
    asm volatile("" ::: "memory");
#pragma unroll
    for (int n = 0; n < 4; ++n) bfr[n] = *(const bf16x8*)&lds[bbq + 4096 + (wn + n * 16) * 32 + ra];
#pragma unroll
    for (int m = 0; m < 4; ++m) af[m] = *(const bf16x8*)&lds[ab + 4096 + (wm + m * 16) * 32 + ra];
    if (pf) { stage2(nb + 4096, Ag, kn + 32); stage2(16384 + nb + 4096, Bg, kn + 32); }
    __builtin_amdgcn_s_barrier();
    asm volatile("" ::: "memory");
    __builtin_amdgcn_s_setprio(1);
#pragma unroll
    for (int m = 0; m < 4; ++m)
#pragma unroll
      for (int n = 0; n < 4; ++n)
        acc[m][n] = __builtin_amdgcn_mfma_f32_16x16x32_bf16(af[m], bfr[n], acc[m][n], 0, 0, 0);
    __builtin_amdgcn_s_setprio(0);

    buf ^= 1;
  }

  const int crow = (lane >> 4) * 4;
  const int ccol = lane & 15;
  float* Pz = P + (size_t)blockIdx.z * M * N;
#pragma unroll
  for (int m = 0; m < 4; ++m)
#pragma unroll
    for (int n = 0; n < 4; ++n) {
      const int gr = m0 + wm + m * 16 + crow;
      const int gc = n0 + wn + n * 16 + ccol;
#pragma unroll
      for (int r = 0; r < 4; ++r)
        Pz[(size_t)(gr + r) * N + gc] = acc[m][n][r];
    }
}

// reduce 2 f32 partials + bias -> out.  n4 = MN/4 in f32x4 units.
__global__ __launch_bounds__(256) void reduce_k(const float* __restrict__ P,
                                                const float* __restrict__ bb1,
                                                float* __restrict__ out,
                                                int n4) {
  const f32x4* p = (const f32x4*)P;
  const f32x4* bv = (const f32x4*)bb1;
  f32x4* o = (f32x4*)out;
  for (int i = blockIdx.x * 256 + threadIdx.x; i < n4; i += gridDim.x * 256) {
    f32x4 v = p[i];
    v += p[i + n4];
    v += bv[i & 255];                  // col = (i*4) % 1024
    o[i] = v;
  }
}

// ---------------------------------------------------------------------------

extern "C" void kernel_launch(void* const* d_in, const int* in_sizes, int n_in,
                              void* d_out, int out_size, void* d_ws, size_t ws_size,
                              hipStream_t stream) {
  const float* x  = (const float*)d_in[0];   // [8,512,1024]
  const float* w0 = (const float*)d_in[1];   // [4096,1024]
  const float* b0 = (const float*)d_in[2];   // [4096]
  const float* w1 = (const float*)d_in[3];   // [1024,4096]
  const float* b1 = (const float*)d_in[4];   // [1024]
  const float* ae = (const float*)d_in[5];   // [3]
  const float* am = (const float*)d_in[6];   // [3]

  char* ws = (char*)d_ws;
  unsigned short* xb   = (unsigned short*)(ws);                    //  8 MiB
  unsigned short* w0e  = (unsigned short*)(ws + (8u  << 20));      //  8 MiB
  unsigned short* w1e  = (unsigned short*)(ws + (16u << 20));      //  8 MiB
  unsigned short* Hbuf = (unsigned short*)(ws + (24u << 20));      // 32 MiB
  float* bb0 = (float*)(ws + (56u << 20));                         // 16 KiB
  float* bb1 = (float*)(ws + (56u << 20) + 16384);                 //  4 KiB
  float* part = (float*)(ws + (57u << 20));                        // 32 MiB (SK2)
  const size_t WS_NEEDED = (57u << 20) + (32u << 20);              // 89 MiB

  conv_all<<<6147, 256, 0, stream>>>(x, w0, b0, w1, b1, ae, am,
                                     xb, w0e, w1e, bb0, bb1);

  dim3 g1(16, 16);  // M/256 x N/256
  gemm256<0><<<g1, 512, 131072, stream>>>(xb, w0e, bb0, Hbuf, 4096, 4096, 1024, 1024);

  if (ws_size >= WS_NEEDED) {
    // SK2 x 128² tiles: 32x8x2 = 512 blocks (2 blocks/CU)
    dim3 g2(32, 8, 2);
    gemm128p<<<g2, 256, 0, stream>>>(Hbuf, w1e, part, 4096, 1024, 4096, 2048);
    reduce_k<<<2048, 256, 0, stream>>>(part, bb1, (float*)d_out, 1048576);
  } else {
    dim3 g2(16, 4);
    gemm256<1><<<g2, 512, 131072, stream>>>(Hbuf, w1e, bb1, d_out, 4096, 1024, 4096, 4096);
  }
}